// Round 8
// baseline (617.858 us; speedup 1.0000x reference)
//
#include <hip/hip_runtime.h>
#include <math.h>

// Problem constants
#define S_LEN 2048
#define DMODEL 512
#define NROWS 4096   // B*S
#define NHEAD 8
#define HDIM 64

typedef __attribute__((ext_vector_type(8))) __bf16 bf16x8;
typedef __attribute__((ext_vector_type(4))) float f32x4;

__device__ inline float bf2f(unsigned short h) {
    unsigned u = ((unsigned)h) << 16;
    return __builtin_bit_cast(float, u);
}
__device__ inline unsigned short f2bf(float f) {
    unsigned u = __builtin_bit_cast(unsigned, f);
    return (unsigned short)((u + 0x7fffu + ((u >> 16) & 1u)) >> 16);
}

// async global->LDS, 16B per lane; LDS dest = wave-uniform base + lane*16
__device__ inline void gl_lds16(const unsigned short* g, unsigned short* l) {
    __builtin_amdgcn_global_load_lds(
        (const __attribute__((address_space(1))) void*)g,
        (__attribute__((address_space(3))) void*)l, 16, 0, 0);
}

// ---------------- weight cast + transpose: Wt[mo][k] = bf16(W[k][mo]) ------
__global__ __launch_bounds__(256) void wcast_t(
    const float* __restrict__ W, unsigned short* __restrict__ Wt, int K, int Mo)
{
    __shared__ float t[32][33];
    const int bx = blockIdx.x * 32;   // Mo
    const int by = blockIdx.y * 32;   // K
    const int tx = threadIdx.x & 31, ty = threadIdx.x >> 5;
    #pragma unroll
    for (int r = 0; r < 4; ++r)
        t[ty + 8 * r][tx] = W[(size_t)(by + ty + 8 * r) * Mo + bx + tx];
    __syncthreads();
    #pragma unroll
    for (int r = 0; r < 4; ++r)
        Wt[(size_t)(bx + ty + 8 * r) * K + by + tx] = f2bf(t[tx][ty + 8 * r]);
}

// 8 square 512x512 weights in one launch (blockIdx.z selects)
__global__ __launch_bounds__(256) void wcast_sq8(
    const float* w0, const float* w1, const float* w2, const float* w3,
    const float* w4, const float* w5, const float* w6, const float* w7,
    unsigned short* __restrict__ dst)
{
    const float* srcs[8] = {w0, w1, w2, w3, w4, w5, w6, w7};
    const float* __restrict__ W = srcs[blockIdx.z];
    unsigned short* __restrict__ Wt = dst + (size_t)blockIdx.z * 512 * 512;
    __shared__ float t[32][33];
    const int bx = blockIdx.x * 32, by = blockIdx.y * 32;
    const int tx = threadIdx.x & 31, ty = threadIdx.x >> 5;
    #pragma unroll
    for (int r = 0; r < 4; ++r)
        t[ty + 8 * r][tx] = W[(size_t)(by + ty + 8 * r) * 512 + bx + tx];
    __syncthreads();
    #pragma unroll
    for (int r = 0; r < 4; ++r)
        Wt[(size_t)(bx + ty + 8 * r) * 512 + by + tx] = f2bf(t[tx][ty + 8 * r]);
}

// ---------------- pack biases: [g_bq|g_bk|g_bv|e_bq|e_bk] ----------------
__global__ __launch_bounds__(256) void pack_bias5(
    const float* __restrict__ b0, const float* __restrict__ b1,
    const float* __restrict__ b2, const float* __restrict__ b3,
    const float* __restrict__ b4, float* __restrict__ dst)
{
    int t = blockIdx.x * 256 + threadIdx.x;   // 0..2559
    const float* srcs[5] = {b0, b1, b2, b3, b4};
    dst[t] = srcs[t >> 9][t & 511];
}

// ---------------- fused pre-elementwise: LN(gene), cast(gene), LN(expr) ----
__global__ __launch_bounds__(256) void elem_pre(
    const float* __restrict__ gene, const float* __restrict__ expr,
    const float* __restrict__ wg, const float* __restrict__ bg,
    const float* __restrict__ we, const float* __restrict__ be,
    unsigned short* __restrict__ lng,   // [4096][512]  LN(gene)
    unsigned short* __restrict__ cat)   // [4096][1024] [bf16(gene) | LN(expr)]
{
    __shared__ float red[16];
    const int row = blockIdx.x, t = threadIdx.x;
    float g0 = gene[(size_t)row * 512 + t], g1 = gene[(size_t)row * 512 + t + 256];
    float e0 = expr[(size_t)row * 512 + t], e1 = expr[(size_t)row * 512 + t + 256];
    float sg = g0 + g1, qg = g0 * g0 + g1 * g1;
    float se = e0 + e1, qe = e0 * e0 + e1 * e1;
    #pragma unroll
    for (int o = 32; o > 0; o >>= 1) {
        sg += __shfl_down(sg, o); qg += __shfl_down(qg, o);
        se += __shfl_down(se, o); qe += __shfl_down(qe, o);
    }
    int wid = t >> 6, lane = t & 63;
    if (lane == 0) { red[wid] = sg; red[4 + wid] = qg; red[8 + wid] = se; red[12 + wid] = qe; }
    __syncthreads();
    float mg_ = (red[0] + red[1] + red[2] + red[3]) * (1.0f / 512.0f);
    float qg_ = (red[4] + red[5] + red[6] + red[7]) * (1.0f / 512.0f);
    float me_ = (red[8] + red[9] + red[10] + red[11]) * (1.0f / 512.0f);
    float qe_ = (red[12] + red[13] + red[14] + red[15]) * (1.0f / 512.0f);
    float rg = rsqrtf(qg_ - mg_ * mg_ + 1e-5f);
    float re = rsqrtf(qe_ - me_ * me_ + 1e-5f);
    lng[(size_t)row * 512 + t]        = f2bf((g0 - mg_) * rg * wg[t] + bg[t]);
    lng[(size_t)row * 512 + t + 256]  = f2bf((g1 - mg_) * rg * wg[t + 256] + bg[t + 256]);
    cat[(size_t)row * 1024 + t]       = f2bf(g0);
    cat[(size_t)row * 1024 + t + 256] = f2bf(g1);
    cat[(size_t)row * 1024 + 512 + t]       = f2bf((e0 - me_) * re * we[t] + be[t]);
    cat[(size_t)row * 1024 + 512 + t + 256] = f2bf((e1 - me_) * re * we[t + 256] + be[t + 256]);
}

// ---------------- dual LayerNorm (x fp32 -> bf16), branch by blockIdx.y ----
__global__ __launch_bounds__(256) void ln2_dual(
    const float* __restrict__ X0, const float* __restrict__ X1,
    const float* __restrict__ w0, const float* __restrict__ b0,
    const float* __restrict__ w1, const float* __restrict__ b1,
    unsigned short* __restrict__ y0, unsigned short* __restrict__ y1)
{
    __shared__ float red[8];
    const int br = blockIdx.y;
    const float* x = br ? X1 : X0;
    const float* w = br ? w1 : w0;
    const float* b = br ? b1 : b0;
    unsigned short* y = br ? y1 : y0;
    const int row = blockIdx.x, t = threadIdx.x;
    float v0 = x[(size_t)row * 512 + t], v1 = x[(size_t)row * 512 + t + 256];
    float s = v0 + v1, q = v0 * v0 + v1 * v1;
    #pragma unroll
    for (int o = 32; o > 0; o >>= 1) { s += __shfl_down(s, o); q += __shfl_down(q, o); }
    int wid = t >> 6, lane = t & 63;
    if (lane == 0) { red[wid] = s; red[4 + wid] = q; }
    __syncthreads();
    float mean = (red[0] + red[1] + red[2] + red[3]) * (1.0f / 512.0f);
    float msq  = (red[4] + red[5] + red[6] + red[7]) * (1.0f / 512.0f);
    float rs = rsqrtf(msq - mean * mean + 1e-5f);
    y[(size_t)row * 512 + t]       = f2bf((v0 - mean) * rs * w[t] + b[t]);
    y[(size_t)row * 512 + t + 256] = f2bf((v1 - mean) * rs * w[t + 256] + b[t + 256]);
}

// ---------------- V transpose x4: (branch, b) by blockIdx.z ----------------
__global__ __launch_bounds__(256) void vtrans4(
    const unsigned short* __restrict__ Vg, const unsigned short* __restrict__ Ve,
    unsigned short* __restrict__ Vtg, unsigned short* __restrict__ Vte)
{
    __shared__ unsigned short t[64][72];
    const int z = blockIdx.z, branch = z >> 1, b = z & 1;
    const unsigned short* V = branch ? Ve : Vg;
    unsigned short* Vt = branch ? Vte : Vtg;
    const int s0 = blockIdx.x * 64, h = blockIdx.y;
    const int tid = threadIdx.x;
    {
        const int r = tid >> 2, c = (tid & 3) * 16;
        const unsigned short* src = V + (size_t)(b * S_LEN + s0 + r) * 512 + h * 64 + c;
        *(int4*)&t[r][c]     = *(const int4*)(src);
        *(int4*)&t[r][c + 8] = *(const int4*)(src + 8);
    }
    __syncthreads();
    {
        const int d = tid >> 2, s = (tid & 3) * 16;
        unsigned short* dst = Vt + ((size_t)((b * 8 + h) * 64 + d)) * S_LEN + s0 + s;
        unsigned short tmp[16];
        #pragma unroll
        for (int e = 0; e < 16; ++e) tmp[e] = t[s + e][d];
        *(int4*)dst       = *(int4*)&tmp[0];
        *(int4*)(dst + 8) = *(int4*)&tmp[8];
    }
}

// ---------------- bf16 MFMA GEMM, 128x128 tile, BK=32, async staging -------
__global__ __launch_bounds__(256) void gemm_mfma(
    const unsigned short* __restrict__ A, int lda,
    const unsigned short* __restrict__ Bt,
    const float* __restrict__ bias,
    const float* __restrict__ R1,
    const unsigned short* __restrict__ R2,
    float* __restrict__ Cf, unsigned short* __restrict__ Cb,
    int K, int Mo, int dogelu)
{
    __shared__ __align__(16) unsigned short As[128 * 32];
    __shared__ __align__(16) unsigned short Bs[128 * 32];
    const int tid = threadIdx.x;
    const int wave = tid >> 6, lane = tid & 63;
    const int wr = wave >> 1, wc = wave & 1;
    const int row0 = blockIdx.y * 128, col0 = blockIdx.x * 128;
    const int l15 = lane & 15, q = lane >> 4;

    f32x4 acc[4][4];
    const f32x4 zz = {0.f, 0.f, 0.f, 0.f};
    #pragma unroll
    for (int i = 0; i < 4; ++i)
        #pragma unroll
        for (int j = 0; j < 4; ++j) acc[i][j] = zz;

    for (int k0 = 0; k0 < K; k0 += 32) {
        #pragma unroll
        for (int r = 0; r < 2; ++r) {
            int idx = r * 256 + tid;
            int row = idx >> 2, kc = idx & 3;
            gl_lds16(&A[(size_t)(row0 + row) * lda + k0 + kc * 8],
                     &As[(size_t)(r * 256 + wave * 64) * 8]);
            gl_lds16(&Bt[(size_t)(col0 + row) * K + k0 + kc * 8],
                     &Bs[(size_t)(r * 256 + wave * 64) * 8]);
        }
        __syncthreads();
        bf16x8 af[4], bfr[4];
        #pragma unroll
        for (int fi = 0; fi < 4; ++fi)
            af[fi] = *(const bf16x8*)&As[(wr * 64 + fi * 16 + l15) * 32 + q * 8];
        #pragma unroll
        for (int fj = 0; fj < 4; ++fj)
            bfr[fj] = *(const bf16x8*)&Bs[(wc * 64 + fj * 16 + l15) * 32 + q * 8];
        #pragma unroll
        for (int fi = 0; fi < 4; ++fi)
            #pragma unroll
            for (int fj = 0; fj < 4; ++fj)
                acc[fi][fj] = __builtin_amdgcn_mfma_f32_16x16x32_bf16(
                    af[fi], bfr[fj], acc[fi][fj], 0, 0, 0);
        __syncthreads();
    }

    #pragma unroll
    for (int fi = 0; fi < 4; ++fi) {
        #pragma unroll
        for (int reg = 0; reg < 4; ++reg) {
            int row = row0 + wr * 64 + fi * 16 + q * 4 + reg;
            #pragma unroll
            for (int fj = 0; fj < 4; ++fj) {
                int col = col0 + wc * 64 + fj * 16 + l15;
                float v = acc[fi][fj][reg] + bias[col];
                if (dogelu) v = 0.5f * v * (1.0f + erff(v * 0.70710678118654752f));
                size_t off = (size_t)row * Mo + col;
                if (R1) v += R1[off];
                if (R2) v += bf2f(R2[off]);
                if (Cb) Cb[off] = f2bf(v);
                else    Cf[off] = v;
            }
        }
    }
}

// ---------------- bf16 MFMA GEMM, 64x64 tile, BK=64, async staging ---------
__global__ __launch_bounds__(256) void gemm_mfma64(
    const unsigned short* __restrict__ A, int lda,
    const unsigned short* __restrict__ Bt,
    const float* __restrict__ bias,
    const float* __restrict__ R1,
    const unsigned short* __restrict__ R2,
    float* __restrict__ Cf, unsigned short* __restrict__ Cb,
    int K, int Mo, int dogelu)
{
    __shared__ __align__(16) unsigned short As[64 * 64];
    __shared__ __align__(16) unsigned short Bs[64 * 64];
    const int tid = threadIdx.x;
    const int wave = tid >> 6, lane = tid & 63;
    const int row0 = blockIdx.y * 64, col0 = blockIdx.x * 64;
    const int l15 = lane & 15, q = lane >> 4;

    f32x4 acc[4];
    const f32x4 zz = {0.f, 0.f, 0.f, 0.f};
    #pragma unroll
    for (int j = 0; j < 4; ++j) acc[j] = zz;

    for (int k0 = 0; k0 < K; k0 += 64) {
        #pragma unroll
        for (int r = 0; r < 2; ++r) {
            int idx = r * 256 + tid;
            int row = idx >> 3, kc = idx & 7;
            gl_lds16(&A[(size_t)(row0 + row) * lda + k0 + kc * 8],
                     &As[(size_t)(r * 256 + wave * 64) * 8]);
            gl_lds16(&Bt[(size_t)(col0 + row) * K + k0 + kc * 8],
                     &Bs[(size_t)(r * 256 + wave * 64) * 8]);
        }
        __syncthreads();
        #pragma unroll
        for (int ks = 0; ks < 2; ++ks) {
            bf16x8 af = *(const bf16x8*)&As[(wave * 16 + l15) * 64 + ks * 32 + q * 8];
            bf16x8 bfr[4];
            #pragma unroll
            for (int fj = 0; fj < 4; ++fj)
                bfr[fj] = *(const bf16x8*)&Bs[(fj * 16 + l15) * 64 + ks * 32 + q * 8];
            #pragma unroll
            for (int fj = 0; fj < 4; ++fj)
                acc[fj] = __builtin_amdgcn_mfma_f32_16x16x32_bf16(af, bfr[fj], acc[fj], 0, 0, 0);
        }
        __syncthreads();
    }

    #pragma unroll
    for (int reg = 0; reg < 4; ++reg) {
        int row = row0 + wave * 16 + q * 4 + reg;
        #pragma unroll
        for (int fj = 0; fj < 4; ++fj) {
            int col = col0 + fj * 16 + l15;
            float v = acc[fj][reg] + bias[col];
            if (dogelu) v = 0.5f * v * (1.0f + erff(v * 0.70710678118654752f));
            size_t off = (size_t)row * Mo + col;
            if (R1) v += R1[off];
            if (R2) v += bf2f(R2[off]);
            if (Cb) Cb[off] = f2bf(v);
            else    Cf[off] = v;
        }
    }
}

// ---------------- dual-job 64x64 GEMM (K=512, Mo=512), job by blockIdx.z ---
__global__ __launch_bounds__(256) void gemm64_dual(
    const unsigned short* A0, const unsigned short* A1, int lda0, int lda1,
    const unsigned short* W0, const unsigned short* W1,
    const float* b0, const float* b1,
    const float* R10, const float* R11,
    float* Cf0, float* Cf1, unsigned short* Cb0, unsigned short* Cb1)
{
    __shared__ __align__(16) unsigned short As[64 * 64];
    __shared__ __align__(16) unsigned short Bs[64 * 64];
    const int j = blockIdx.z;
    const unsigned short* __restrict__ A = j ? A1 : A0;
    const int lda = j ? lda1 : lda0;
    const unsigned short* __restrict__ Bt = j ? W1 : W0;
    const float* __restrict__ bias = j ? b1 : b0;
    const float* __restrict__ R1 = j ? R11 : R10;
    float* __restrict__ Cf = j ? Cf1 : Cf0;
    unsigned short* __restrict__ Cb = j ? Cb1 : Cb0;

    const int tid = threadIdx.x;
    const int wave = tid >> 6, lane = tid & 63;
    const int row0 = blockIdx.y * 64, col0 = blockIdx.x * 64;
    const int l15 = lane & 15, q = lane >> 4;

    f32x4 acc[4];
    const f32x4 zz = {0.f, 0.f, 0.f, 0.f};
    #pragma unroll
    for (int jj = 0; jj < 4; ++jj) acc[jj] = zz;

    for (int k0 = 0; k0 < 512; k0 += 64) {
        #pragma unroll
        for (int r = 0; r < 2; ++r) {
            int idx = r * 256 + tid;
            int row = idx >> 3, kc = idx & 7;
            gl_lds16(&A[(size_t)(row0 + row) * lda + k0 + kc * 8],
                     &As[(size_t)(r * 256 + wave * 64) * 8]);
            gl_lds16(&Bt[(size_t)(col0 + row) * 512 + k0 + kc * 8],
                     &Bs[(size_t)(r * 256 + wave * 64) * 8]);
        }
        __syncthreads();
        #pragma unroll
        for (int ks = 0; ks < 2; ++ks) {
            bf16x8 af = *(const bf16x8*)&As[(wave * 16 + l15) * 64 + ks * 32 + q * 8];
            bf16x8 bfr[4];
            #pragma unroll
            for (int fj = 0; fj < 4; ++fj)
                bfr[fj] = *(const bf16x8*)&Bs[(fj * 16 + l15) * 64 + ks * 32 + q * 8];
            #pragma unroll
            for (int fj = 0; fj < 4; ++fj)
                acc[fj] = __builtin_amdgcn_mfma_f32_16x16x32_bf16(af, bfr[fj], acc[fj], 0, 0, 0);
        }
        __syncthreads();
    }

    #pragma unroll
    for (int reg = 0; reg < 4; ++reg) {
        int row = row0 + wave * 16 + q * 4 + reg;
        #pragma unroll
        for (int fj = 0; fj < 4; ++fj) {
            int col = col0 + fj * 16 + l15;
            float v = acc[fj][reg] + bias[col];
            size_t off = (size_t)row * 512 + col;
            if (R1) v += R1[off];
            if (Cb) Cb[off] = f2bf(v);
            else    Cf[off] = v;
        }
    }
}

// ---------------- fused MFMA flash attention (both branches, pipelined) ----
// grid (32 q-tiles, 16 bh, 2 branches). Register-prefetch software pipeline:
// global loads for iter k+1 issued before compute of iter k (overlaps the
// ~600-900 cyc L3/HBM latency of the M/K/V staging with MFMA+softmax).
__global__ __launch_bounds__(256, 4) void attn_fused(
    const unsigned short* __restrict__ QKg,   // [4096][1024] Q|K
    const unsigned short* __restrict__ QKe,
    const unsigned short* __restrict__ Vtg,   // [16 bh][64 d][2048 s]
    const unsigned short* __restrict__ Vte,
    const float* __restrict__ M,
    unsigned short* __restrict__ Og,          // [4096][512]
    unsigned short* __restrict__ Oe)
{
    __shared__ __align__(16) unsigned short Ks[64 * 72];
    __shared__ __align__(16) unsigned short Vs[64 * 72];
    __shared__ __align__(16) float Ms[4][16 * 68];   // per-wave M; P aliases

    const int br = blockIdx.z;
    const unsigned short* QK = br ? QKe : QKg;
    const unsigned short* Vt = br ? Vte : Vtg;
    unsigned short* O = br ? Oe : Og;

    const int bh = blockIdx.y, b = bh >> 3, h = bh & 7;
    const int q0 = blockIdx.x * 64;
    const int tid = threadIdx.x, wave = tid >> 6, lane = tid & 63;
    const int l15 = lane & 15, quad = lane >> 4;
    const int iRow = q0 + wave * 16 + l15;

    unsigned short* Ps = (unsigned short*)&Ms[wave][0];   // [16][72] shorts

    // Q fragments (B-operand), pre-scaled by 1/8 (exact in bf16)
    bf16x8 qf[2];
    {
        const unsigned short* qp = QK + (size_t)(b * S_LEN + iRow) * 1024 + h * HDIM + quad * 8;
        #pragma unroll
        for (int ks = 0; ks < 2; ++ks) {
            union { bf16x8 v; unsigned short u[8]; } tq;
            tq.v = *(const bf16x8*)(qp + ks * 32);
            #pragma unroll
            for (int e = 0; e < 8; ++e) tq.u[e] = f2bf(bf2f(tq.u[e]) * 0.125f);
            qf[ks] = tq.v;
        }
    }

    float rm = -INFINITY, rZ = 0.f, rZm = 0.f;
    f32x4 oacc[4];
    const f32x4 zz = {0.f, 0.f, 0.f, 0.f};
    #pragma unroll
    for (int dt = 0; dt < 4; ++dt) oacc[dt] = zz;

    const int srow = tid >> 3;            // 0..31
    const int scol = (tid & 7) * 8;       // 0..56 shorts
    const unsigned short* kg = QK + 512 + ((size_t)b * S_LEN) * 1024 + h * HDIM + scol;
    const unsigned short* vg = Vt + ((size_t)bh * 64 + srow) * S_LEN + scol;
    const float* mg = M + (size_t)b * S_LEN * S_LEN + (size_t)(q0 + wave * 16) * S_LEN;

    // prologue prefetch (iter 0)
    int4 pK0 = *(const int4*)(kg + (size_t)(srow) * 1024);
    int4 pK1 = *(const int4*)(kg + (size_t)(srow + 32) * 1024);
    int4 pV0 = *(const int4*)(vg);
    int4 pV1 = *(const int4*)(vg + 32 * S_LEN);
    float4 pM[4];
    #pragma unroll
    for (int c = 0; c < 4; ++c)
        pM[c] = *(const float4*)(mg + (size_t)(c * 4 + quad) * S_LEN + l15 * 4);

    for (int k0 = 0; k0 < S_LEN; k0 += 64) {
        __syncthreads();   // all waves done with Ks/Vs of prev iter
        *(int4*)&Ks[srow * 72 + scol]        = pK0;
        *(int4*)&Ks[(srow + 32) * 72 + scol] = pK1;
        *(int4*)&Vs[srow * 72 + scol]        = pV0;
        *(int4*)&Vs[(srow + 32) * 72 + scol] = pV1;
        #pragma unroll
        for (int c = 0; c < 4; ++c)
            *(float4*)&Ms[wave][(c * 4 + quad) * 68 + l15 * 4] = pM[c];
        // issue next-iter loads; they complete during this iter's compute
        int kn = k0 + 64;
        if (kn < S_LEN) {
            pK0 = *(const int4*)(kg + (size_t)(kn + srow) * 1024);
            pK1 = *(const int4*)(kg + (size_t)(kn + srow + 32) * 1024);
            pV0 = *(const int4*)(vg + kn);
            pV1 = *(const int4*)(vg + 32 * S_LEN + kn);
            #pragma unroll
            for (int c = 0; c < 4; ++c)
                pM[c] = *(const float4*)(mg + (size_t)(c * 4 + quad) * S_LEN + kn + l15 * 4);
        }
        __syncthreads();

        // M for my 16 q-rows (read BEFORE Ps overwrites region)
        float4 m4[4];
        #pragma unroll
        for (int jt = 0; jt < 4; ++jt)
            m4[jt] = *(const float4*)&Ms[wave][l15 * 68 + jt * 16 + quad * 4];

        f32x4 sacc[4];
        #pragma unroll
        for (int jt = 0; jt < 4; ++jt) sacc[jt] = zz;
        #pragma unroll
        for (int jt = 0; jt < 4; ++jt) {
            bf16x8 kf0 = *(const bf16x8*)&Ks[(jt * 16 + l15) * 72 + quad * 8];
            bf16x8 kf1 = *(const bf16x8*)&Ks[(jt * 16 + l15) * 72 + 32 + quad * 8];
            sacc[jt] = __builtin_amdgcn_mfma_f32_16x16x32_bf16(kf0, qf[0], sacc[jt], 0, 0, 0);
            sacc[jt] = __builtin_amdgcn_mfma_f32_16x16x32_bf16(kf1, qf[1], sacc[jt], 0, 0, 0);
        }

        float mx = -INFINITY;
        #pragma unroll
        for (int jt = 0; jt < 4; ++jt) {
            float mm[4] = {m4[jt].x, m4[jt].y, m4[jt].z, m4[jt].w};
            #pragma unroll
            for (int r = 0; r < 4; ++r) {
                sacc[jt][r] = sacc[jt][r] * mm[r];
                mx = fmaxf(mx, sacc[jt][r]);
            }
        }
        mx = fmaxf(mx, __shfl_xor(mx, 16));
        mx = fmaxf(mx, __shfl_xor(mx, 32));
        float mn = fmaxf(rm, mx);
        float al = __expf(rm - mn);
        rm = mn; rZ *= al; rZm *= al;
        #pragma unroll
        for (int dt = 0; dt < 4; ++dt)
            #pragma unroll
            for (int r = 0; r < 4; ++r) oacc[dt][r] *= al;

        float z = 0.f, zm = 0.f;
        #pragma unroll
        for (int jt = 0; jt < 4; ++jt) {
            float mm[4] = {m4[jt].x, m4[jt].y, m4[jt].z, m4[jt].w};
            float pv[4];
            #pragma unroll
            for (int r = 0; r < 4; ++r) {
                float e = __expf(sacc[jt][r] - mn);
                float pm = e * mm[r];
                z += e; zm += pm; pv[r] = pm;
            }
            unsigned lo = (unsigned)f2bf(pv[0]) | ((unsigned)f2bf(pv[1]) << 16);
            unsigned hi = (unsigned)f2bf(pv[2]) | ((unsigned)f2bf(pv[3]) << 16);
            uint2 pk; pk.x = lo; pk.y = hi;
            *(uint2*)&Ps[l15 * 72 + jt * 16 + quad * 4] = pk;
        }
        z  += __shfl_xor(z, 16);  z  += __shfl_xor(z, 32);
        zm += __shfl_xor(zm, 16); zm += __shfl_xor(zm, 32);
        rZ += z; rZm += zm;

        bf16x8 pf0 = *(const bf16x8*)&Ps[l15 * 72 + quad * 8];
        bf16x8 pf1 = *(const bf16x8*)&Ps[l15 * 72 + 32 + quad * 8];
        #pragma unroll
        for (int dt = 0; dt < 4; ++dt) {
            bf16x8 vf0 = *(const bf16x8*)&Vs[(dt * 16 + l15) * 72 + quad * 8];
            bf16x8 vf1 = *(const bf16x8*)&Vs[(dt * 16 + l15) * 72 + 32 + quad * 8];
            oacc[dt] = __builtin_amdgcn_mfma_f32_16x16x32_bf16(vf0, pf0, oacc[dt], 0, 0, 0);
            oacc[dt] = __builtin_amdgcn_mfma_f32_16x16x32_bf16(vf1, pf1, oacc[dt], 0, 0, 0);
        }
    }

    float inv = 1.0f / (rZm + 1e-8f * rZ);
    #pragma unroll
    for (int dt = 0; dt < 4; ++dt) {
        ushort4 o4;
        o4.x = f2bf(oacc[dt][0] * inv); o4.y = f2bf(oacc[dt][1] * inv);
        o4.z = f2bf(oacc[dt][2] * inv); o4.w = f2bf(oacc[dt][3] * inv);
        *(ushort4*)(O + (size_t)(b * S_LEN + iRow) * DMODEL + h * HDIM + dt * 16 + quad * 4) = o4;
    }
}

// ---------------- launch ----------------
extern "C" void kernel_launch(void* const* d_in, const int* in_sizes, int n_in,
                              void* d_out, int out_size, void* d_ws, size_t ws_size,
                              hipStream_t stream)
{
    const float* gene_emb = (const float*)d_in[0];
    const float* expr_emb = (const float*)d_in[1];
    const float* M        = (const float*)d_in[2];
    const float* g_wq = (const float*)d_in[3];
    const float* g_wk = (const float*)d_in[4];
    const float* g_wv = (const float*)d_in[5];
    const float* g_wo = (const float*)d_in[6];
    const float* g_bq = (const float*)d_in[7];
    const float* g_bk = (const float*)d_in[8];
    const float* g_bv = (const float*)d_in[9];
    const float* g_bo = (const float*)d_in[10];
    const float* e_wf = (const float*)d_in[11];
    const float* e_bf = (const float*)d_in[12];
    const float* e_wq = (const float*)d_in[13];
    const float* e_wk = (const float*)d_in[14];
    const float* e_wv = (const float*)d_in[15];
    const float* e_wo = (const float*)d_in[16];
    const float* e_bq = (const float*)d_in[17];
    const float* e_bk = (const float*)d_in[18];
    const float* e_bv = (const float*)d_in[19];
    const float* e_bo = (const float*)d_in[20];
    const float* ln_g1_w = (const float*)d_in[21];
    const float* ln_g2_w = (const float*)d_in[22];
    const float* ln_e1_w = (const float*)d_in[23];
    const float* ln_e2_w = (const float*)d_in[24];
    const float* ln_g1_b = (const float*)d_in[25];
    const float* ln_g2_b = (const float*)d_in[26];
    const float* ln_e1_b = (const float*)d_in[27];
    const float* ln_e2_b = (const float*)d_in[28];
    const float* fg_w1 = (const float*)d_in[29];
    const float* fg_b1 = (const float*)d_in[30];
    const float* fg_w2 = (const float*)d_in[31];
    const float* fg_b2 = (const float*)d_in[32];
    const float* fe_w1 = (const float*)d_in[33];
    const float* fe_b1 = (const float*)d_in[34];
    const float* fe_w2 = (const float*)d_in[35];
    const float* fe_b2 = (const float*)d_in[36];

    float* out_gene = (float*)d_out;
    float* out_expr = out_gene + (size_t)NROWS * DMODEL;

    // ---- workspace map (MB offsets), peak 54 MB ----
    // W: 0-4 sq8 | 4-5 ewf | 5-7 w1slot (fg_w1 -> fe_w1) | 7-9 w2slot | 9 bias
    // A 10-14: LNg -> Fe -> At_g        B 14-22: cat -> X_g (fp32)
    // C 22-30: QKg -> X_e (fp32)        D 30-38: QKe -> A16g|A16e
    // E 38-42: Vg -> At_e               F 42-46: Ve
    // G 46-50: Vt_g                     H 50-54: Vt_e
    // hidden 38-54 (post-attn; E/F/G/H dead)
    char* ws = (char*)d_ws;
    const size_t MB1 = 1024 * 1024;
    unsigned short* sq8    = (unsigned short*)(ws);
    unsigned short* gwv_t  = sq8 + 2 * 512 * 512;
    unsigned short* gwo_t  = sq8 + 3 * 512 * 512;
    unsigned short* ewqk_t = sq8 + 4 * 512 * 512;
    unsigned short* ewv_t  = sq8 + 6 * 512 * 512;
    unsigned short* ewo_t  = sq8 + 7 * 512 * 512;
    unsigned short* ewf_t  = (unsigned short*)(ws + 4 * MB1);
    unsigned short* w1slot = (unsigned short*)(ws + 5 * MB1);
    unsigned short* w2slot = (unsigned short*)(ws + 7 * MB1);
    float* biasAll = (float*)(ws + 9 * MB1);   // [g_bq|g_bk|g_bv|e_bq|e_bk]

    unsigned short* bufLNg = (unsigned short*)(ws + 10 * MB1);
    unsigned short* bufFe  = (unsigned short*)(ws + 10 * MB1);
    unsigned short* bufAtg = (unsigned short*)(ws + 10 * MB1);
    unsigned short* bufCat = (unsigned short*)(ws + 14 * MB1);
    float*          bufXg  = (float*)(ws + 14 * MB1);
    unsigned short* bufQKg = (unsigned short*)(ws + 22 * MB1);
    float*          bufXe  = (float*)(ws + 22 * MB1);
    unsigned short* bufQKe = (unsigned short*)(ws + 30 * MB1);
    unsigned short* bufA16g = (unsigned short*)(ws + 30 * MB1);
    unsigned short* bufA16e = (unsigned short*)(ws + 34 * MB1);
    unsigned short* bufVg  = (unsigned short*)(ws + 38 * MB1);
    unsigned short* bufAte = (unsigned short*)(ws + 38 * MB1);
    unsigned short* bufVe  = (unsigned short*)(ws + 42 * MB1);
    unsigned short* bufVtg = (unsigned short*)(ws + 46 * MB1);
    unsigned short* bufVte = (unsigned short*)(ws + 50 * MB1);
    unsigned short* bufHid = (unsigned short*)(ws + 38 * MB1);

    dim3 blk(256);
    dim3 gQK(8, 32);           // 128-tile, Mo=1024
    dim3 gFFN1(16, 32);        // 128-tile, Mo=2048
    dim3 g64(8, 64);           // 64-tile, Mo=512
    dim3 g64d(8, 64, 2);
    dim3 attn_grid(S_LEN / 64, 16, 2);
    dim3 vt_grid(S_LEN / 64, NHEAD, 4);

    // ---- prep ----
    wcast_sq8<<<dim3(16, 16, 8), blk, 0, stream>>>(
        g_wq, g_wk, g_wv, g_wo, e_wq, e_wk, e_wv, e_wo, sq8);
    wcast_t<<<dim3(16, 32), blk, 0, stream>>>(e_wf, ewf_t, 1024, 512);
    wcast_t<<<dim3(64, 16), blk, 0, stream>>>(fg_w1, w1slot, 512, 2048);
    wcast_t<<<dim3(16, 64), blk, 0, stream>>>(fg_w2, w2slot, 2048, 512);
    pack_bias5<<<dim3(10), blk, 0, stream>>>(g_bq, g_bk, g_bv, e_bq, e_bk, biasAll);

    // ---- fused elementwise pre ----
    elem_pre<<<dim3(NROWS), blk, 0, stream>>>(
        gene_emb, expr_emb, ln_g1_w, ln_g1_b, ln_e1_w, ln_e1_b, bufLNg, bufCat);

    // ---- both V projections (dual), then all V transposes ----
    gemm64_dual<<<g64d, blk, 0, stream>>>(
        bufLNg, bufCat + 512, 512, 1024, gwv_t, ewv_t, biasAll + 1024, e_bv,
        nullptr, nullptr, nullptr, nullptr, bufVg, bufVe);
    vtrans4<<<vt_grid, blk, 0, stream>>>(bufVg, bufVe, bufVtg, bufVte);

    // ---- QK projections ----
    gemm_mfma<<<gQK, blk, 0, stream>>>(bufLNg, 512, sq8, biasAll, nullptr, nullptr, nullptr, bufQKg, 512, 1024, 0);
    gemm_mfma64<<<g64, blk, 0, stream>>>(bufCat, 1024, ewf_t, e_bf, nullptr, nullptr, nullptr, bufFe, 1024, 512, 0);
    gemm_mfma<<<gQK, blk, 0, stream>>>(bufFe, 512, ewqk_t, biasAll + 1536, nullptr, nullptr, nullptr, bufQKe, 512, 1024, 0);

    // ---- fused attention (both branches, one dispatch) ----
    attn_fused<<<attn_grid, blk, 0, stream>>>(bufQKg, bufQKe, bufVtg, bufVte, M, bufAtg, bufAte);

    // ---- O-projection + residual (dual) ----
    gemm64_dual<<<g64d, blk, 0, stream>>>(
        bufAtg, bufAte, 512, 512, gwo_t, ewo_t, g_bo, e_bo,
        gene_emb, expr_emb, bufXg, bufXe, nullptr, nullptr);

    // ---- LN2 (dual) ----
    ln2_dual<<<dim3(NROWS, 2), blk, 0, stream>>>(
        bufXg, bufXe, ln_g2_w, ln_g2_b, ln_e2_w, ln_e2_b, bufA16g, bufA16e);

    // ---- gene FFN ----
    gemm_mfma<<<gFFN1, blk, 0, stream>>>(bufA16g, 512, w1slot, fg_b1, nullptr, nullptr, nullptr, bufHid, 512, 2048, 1);
    gemm_mfma64<<<g64, blk, 0, stream>>>(bufHid, 2048, w2slot, fg_b2, bufXg, bufA16g, out_gene, nullptr, 2048, 512, 0);

    // ---- swap FFN weights, expr FFN ----
    wcast_t<<<dim3(64, 16), blk, 0, stream>>>(fe_w1, w1slot, 512, 2048);
    wcast_t<<<dim3(16, 64), blk, 0, stream>>>(fe_w2, w2slot, 2048, 512);
    gemm_mfma<<<gFFN1, blk, 0, stream>>>(bufA16e, 512, w1slot, fe_b1, nullptr, nullptr, nullptr, bufHid, 512, 2048, 1);
    gemm_mfma64<<<g64, blk, 0, stream>>>(bufHid, 2048, w2slot, fe_b2, bufXe, bufA16e, out_expr, nullptr, 2048, 512, 0);
}